// Round 2
// baseline (1019.587 us; speedup 1.0000x reference)
//
#include <hip/hip_runtime.h>
#include <cstdint>

#define N_NODES   10000
#define N_EDGES   640000
#define NODE_OUT  (N_NODES * 128)       // 1,280,000 node-output floats

typedef __bf16 bf16;
typedef bf16  bf16x8 __attribute__((ext_vector_type(8)));
typedef float f32x4  __attribute__((ext_vector_type(4)));

// transposed bf16 weight offsets inside ws ([N][K] row-major, elements)
#define EW1T_OFF 0        // 128 x 384
#define EW2T_OFF 49152    // 128 x 128
#define NW1T_OFF 65536    // 128 x 256
#define NW2T_OFF 98304    // 128 x 128

// -------- weight convert+transpose: fp32 W[K][N] -> bf16 WT[N][K] --------
__global__ void transpose_weights(const float* __restrict__ eW1, const float* __restrict__ eW2,
                                  const float* __restrict__ nW1, const float* __restrict__ nW2,
                                  bf16* __restrict__ wt) {
  int gid = blockIdx.x * 256 + threadIdx.x;   // 448*256 = 114688 exactly
  const float* src; bf16* dst; int K, off;
  if (gid < 49152)      { src = eW1; dst = wt + EW1T_OFF; K = 384; off = gid; }
  else if (gid < 65536) { src = eW2; dst = wt + EW2T_OFF; K = 128; off = gid - 49152; }
  else if (gid < 98304) { src = nW1; dst = wt + NW1T_OFF; K = 256; off = gid - 65536; }
  else                  { src = nW2; dst = wt + NW2T_OFF; K = 128; off = gid - 98304; }
  int k = off >> 7, n = off & 127;
  dst[n * K + k] = (bf16)src[off];
}

__device__ __forceinline__ float softplus_f(float v) {
  return v > 20.f ? v : __logf(1.f + __expf(v));
}

// load 8 consecutive fp32 and round to a bf16x8 fragment
__device__ __forceinline__ bf16x8 load_cvt8(const float* __restrict__ src) {
  float4 f0 = *(const float4*)src;
  float4 f1 = *(const float4*)(src + 4);
  bf16x8 h;
  h[0] = (bf16)f0.x; h[1] = (bf16)f0.y; h[2] = (bf16)f0.z; h[3] = (bf16)f0.w;
  h[4] = (bf16)f1.x; h[5] = (bf16)f1.y; h[6] = (bf16)f1.z; h[7] = (bf16)f1.w;
  return h;
}

// One GEMM over the edge tile: C[128,128] = A(sA slots SLOT_BASE..) x WT^T.
// sA: [128 rows][48 slots of 16B], physical slot = logical ^ (row & 7).
// sB: 2 x 4096-elem chunk buffers, slot s=(w*64+l) holds WT[n=w*16+(l&15)][k=(l>>4)*8..+7]
template <int K, int SLOT_BASE>
__device__ __forceinline__ void run_gemm(const bf16* __restrict__ WT,
                                         const bf16* sA, bf16* sB,
                                         int wave, int lane, int m0, int n0,
                                         f32x4 (&acc)[2][4]) {
  const int ln15 = lane & 15, lq = lane >> 4;
  constexpr int NC = K >> 5;
  const int r0 = m0 + ln15, r1 = r0 + 16;
  const int sw = ln15 & 7;                    // == r0&7 == r1&7
  #pragma unroll
  for (int tm = 0; tm < 2; ++tm)
    #pragma unroll
    for (int tn = 0; tn < 4; ++tn)
      acc[tm][tn] = f32x4{0.f, 0.f, 0.f, 0.f};

  const bf16* wsrc = WT + (wave * 16 + ln15) * K + lq * 8;
  uint4 pre = *(const uint4*)wsrc;            // prefetch chunk 0
  const int bslot = (wave * 64 + lane) * 8;
  const int tb = n0 >> 4;

  #pragma unroll
  for (int c = 0; c < NC; ++c) {
    bf16* buf = sB + (c & 1) * 4096;
    *(uint4*)&buf[bslot] = pre;               // publish chunk c
    if (c + 1 < NC) pre = *(const uint4*)(wsrc + (c + 1) * 32);  // prefetch c+1
    __syncthreads();                          // chunk c visible; c-2 reads drained
    const int ls = SLOT_BASE + (c << 2) + lq;
    bf16x8 a0 = *(const bf16x8*)&sA[r0 * 384 + ((ls ^ sw) << 3)];
    bf16x8 a1 = *(const bf16x8*)&sA[r1 * 384 + ((ls ^ sw) << 3)];
    #pragma unroll
    for (int tn = 0; tn < 4; ++tn) {
      bf16x8 b = *(const bf16x8*)&buf[((tb + tn) * 64 + lane) * 8];
      acc[0][tn] = __builtin_amdgcn_mfma_f32_16x16x32_bf16(a0, b, acc[0][tn], 0, 0, 0);
      acc[1][tn] = __builtin_amdgcn_mfma_f32_16x16x32_bf16(a1, b, acc[1][tn], 0, 0, 0);
    }
  }
  __syncthreads();                            // all frag reads done before epilogue writes
}

// ---------------- fused per-edge MLP ----------------
__global__ void __launch_bounds__(512, 2)
fused_mpnn(const float* __restrict__ x, const int* __restrict__ eidx,
           const float* __restrict__ edge_attr,
           const float* __restrict__ eb1, const float* __restrict__ eb2,
           const float* __restrict__ nb1, const float* __restrict__ nb2,
           const bf16* __restrict__ wt,
           float* __restrict__ node_out, float* __restrict__ edge_out)
{
  extern __shared__ char smem[];
  bf16* sA = (bf16*)smem;               // [128][384] swizzled, 98,304 B
  bf16* sB = (bf16*)(smem + 98304);     // 2 x 8,192 B chunk buffers

  const int tid  = threadIdx.x;
  const int wave = tid >> 6, lane = tid & 63;
  const int ln15 = lane & 15, lq = lane >> 4;
  const int m0 = (wave >> 1) * 32;      // 0,32,64,96
  const int n0 = (wave & 1) * 64;       // 0,64
  const int e0 = blockIdx.x * 128;

  // ---- stage A tile: slots 0-15 x_row | 16-31 x_col | 32-47 edge_attr ----
  #pragma unroll
  for (int it = 0; it < 12; ++it) {
    int j  = it * 512 + tid;            // 0..6143 16B-LDS-chunks
    int region = j >> 11;               // uniform per it
    int jj = j & 2047;
    int e  = jj >> 4, pl = jj & 15;     // physical slot within region
    int lp = pl ^ (e & 7);              // logical slot this thread stages
    const float* src;
    if (region == 0)      src = x + (size_t)eidx[e0 + e] * 128 + lp * 8;
    else if (region == 1) src = x + (size_t)eidx[N_EDGES + e0 + e] * 128 + lp * 8;
    else                  src = edge_attr + (size_t)(e0 + e) * 128 + lp * 8;
    *(bf16x8*)&sA[e * 384 + ((region << 4) + pl) * 8] = load_cvt8(src);
  }
  // (visibility of sA guaranteed by first __syncthreads inside run_gemm)

  f32x4 acc[2][4];

  // ---- GEMM1: [x_row|x_col|edge_attr] @ eW1, softplus -> C1 (slots 32-47) ----
  run_gemm<384, 0>(wt + EW1T_OFF, sA, sB, wave, lane, m0, n0, acc);
  {
    float bias[4];
    #pragma unroll
    for (int tn = 0; tn < 4; ++tn) bias[tn] = eb1[n0 + tn * 16 + ln15];
    #pragma unroll
    for (int tm = 0; tm < 2; ++tm)
      #pragma unroll
      for (int tn = 0; tn < 4; ++tn)
        #pragma unroll
        for (int r = 0; r < 4; ++r) {
          float v = softplus_f(acc[tm][tn][r] + bias[tn]);
          int row = m0 + tm * 16 + lq * 4 + r;
          int col = n0 + tn * 16 + ln15;
          int ls  = 32 + (col >> 3);
          sA[row * 384 + ((ls ^ (row & 7)) << 3) + (col & 7)] = (bf16)v;
        }
  }

  // ---- GEMM2: C1 @ eW2 + eb2 -> edge_out (fp32 global) and C2 (slots 16-31) ----
  run_gemm<128, 32>(wt + EW2T_OFF, sA, sB, wave, lane, m0, n0, acc);
  {
    float bias[4];
    #pragma unroll
    for (int tn = 0; tn < 4; ++tn) bias[tn] = eb2[n0 + tn * 16 + ln15];
    #pragma unroll
    for (int tm = 0; tm < 2; ++tm)
      #pragma unroll
      for (int tn = 0; tn < 4; ++tn)
        #pragma unroll
        for (int r = 0; r < 4; ++r) {
          float v = acc[tm][tn][r] + bias[tn];
          int row = m0 + tm * 16 + lq * 4 + r;
          int col = n0 + tn * 16 + ln15;
          edge_out[(size_t)(e0 + row) * 128 + col] = v;
          int ls = 16 + (col >> 3);
          sA[row * 384 + ((ls ^ (row & 7)) << 3) + (col & 7)] = (bf16)v;
        }
  }

  // ---- GEMM3: [x_row|C2] @ nW1, softplus -> C3 (slots 32-47) ----
  run_gemm<256, 0>(wt + NW1T_OFF, sA, sB, wave, lane, m0, n0, acc);
  {
    float bias[4];
    #pragma unroll
    for (int tn = 0; tn < 4; ++tn) bias[tn] = nb1[n0 + tn * 16 + ln15];
    #pragma unroll
    for (int tm = 0; tm < 2; ++tm)
      #pragma unroll
      for (int tn = 0; tn < 4; ++tn)
        #pragma unroll
        for (int r = 0; r < 4; ++r) {
          float v = softplus_f(acc[tm][tn][r] + bias[tn]);
          int row = m0 + tm * 16 + lq * 4 + r;
          int col = n0 + tn * 16 + ln15;
          int ls  = 32 + (col >> 3);
          sA[row * 384 + ((ls ^ (row & 7)) << 3) + (col & 7)] = (bf16)v;
        }
  }

  // ---- GEMM4: C3 @ nW2 + nb2 -> fp32 atomic scatter into node_out by col ----
  run_gemm<128, 32>(wt + NW2T_OFF, sA, sB, wave, lane, m0, n0, acc);
  {
    float bias[4];
    #pragma unroll
    for (int tn = 0; tn < 4; ++tn) bias[tn] = nb2[n0 + tn * 16 + ln15];
    #pragma unroll
    for (int tm = 0; tm < 2; ++tm) {
      int nodes[4];
      #pragma unroll
      for (int r = 0; r < 4; ++r)
        nodes[r] = eidx[N_EDGES + e0 + m0 + tm * 16 + lq * 4 + r];
      #pragma unroll
      for (int tn = 0; tn < 4; ++tn) {
        int col = n0 + tn * 16 + ln15;
        #pragma unroll
        for (int r = 0; r < 4; ++r) {
          float v = acc[tm][tn][r] + bias[tn];
          unsafeAtomicAdd(&node_out[(size_t)nodes[r] * 128 + col], v);
        }
      }
    }
  }
}

extern "C" void kernel_launch(void* const* d_in, const int* in_sizes, int n_in,
                              void* d_out, int out_size, void* d_ws, size_t ws_size,
                              hipStream_t stream) {
  const float* x    = (const float*)d_in[0];
  const int*   eidx = (const int*)d_in[1];
  const float* ea   = (const float*)d_in[2];
  const float* nW1  = (const float*)d_in[3];
  const float* nb1  = (const float*)d_in[4];
  const float* nW2  = (const float*)d_in[5];
  const float* nb2  = (const float*)d_in[6];
  const float* eW1  = (const float*)d_in[7];
  const float* eb1  = (const float*)d_in[8];
  const float* eW2  = (const float*)d_in[9];
  const float* eb2  = (const float*)d_in[10];

  bf16*  wt        = (bf16*)d_ws;                 // 114,688 bf16 = 229,376 B
  float* out_nodes = (float*)d_out;               // [10000,128]
  float* out_edges = out_nodes + NODE_OUT;        // [640000,128]

  hipMemsetAsync(out_nodes, 0, NODE_OUT * sizeof(float), stream);
  transpose_weights<<<448, 256, 0, stream>>>(eW1, eW2, nW1, nW2, wt);
  fused_mpnn<<<N_EDGES / 128, 512, 98304 + 16384, stream>>>(
      x, eidx, ea, eb1, eb2, nb1, nb2, wt, out_nodes, out_edges);
}